// Round 7
// baseline (152.052 us; speedup 1.0000x reference)
//
#include <hip/hip_runtime.h>
#include <hip/hip_bf16.h>

// SparseAttention B=1,H=8,S=4096,D=32 fp32; mask [S,S] as int32.
// R19: scalarize attn addressing. R18's reg-pipeline dropped attn below
// the 41us fill tax (top-5 = all fills) -> remaining attn cost is VALU
// issue, half of it 64-bit VECTOR address math (w=tid>>6 is wave-uniform
// but unprovable -> v_lshl_add_u64 per load). Fix: readfirstlane(w*8)
// -> SGPR kt-strip base; LOADT takes a LITERAL tile index so every load
// is {SGPR base + imm + fixed lane offset} = zero per-load VALU.
// Mask loads likewise via two scalar base pointers. s_setprio(1) around
// compute cluster (T5; attn-proven +4-7%). Rest = R18 verbatim:
// 2-deep register pipeline, parity-static indices, sched_barrier fences,
// 1024 blocks x 512 thr, q-tile 32, 8 waves x 8-kt strips, barrier-free,
// swapped-operand QK^T, V pre-permuted, per-lane u16 mask, ones-MFMA
// row-sum, head-per-XCD swizzle. Prep unchanged (never ranked in top-5).

#define S_  4096
#define D_  32
#define H_  8

typedef _Float16 half8 __attribute__((ext_vector_type(8)));
typedef __fp16 fp16x2 __attribute__((ext_vector_type(2)));
typedef short short8 __attribute__((ext_vector_type(8)));
typedef short short4v __attribute__((ext_vector_type(4)));
typedef float float4v __attribute__((ext_vector_type(4)));
typedef unsigned short ushort_t;
typedef unsigned int u32;

#if __has_builtin(__builtin_amdgcn_exp2f)
#define EXP2(x) __builtin_amdgcn_exp2f(x)
#else
#define EXP2(x) exp2f(x)
#endif

#if __has_builtin(__builtin_amdgcn_sbfe)
#define SEXT_BIT(v, b) ((u32)__builtin_amdgcn_sbfe((int)(v), (b), 1))
#else
#define SEXT_BIT(v, b) ((u32)(((int)((v) << (31 - (b)))) >> 31))
#endif

__device__ inline ushort_t f2h(float x) {
    union { _Float16 h; ushort_t u; } c; c.h = (_Float16)x; return c.u;
}

// ---------------- fused pre-pass (unchanged from R13-R18, proven) --------
// blocks [0,512): Q fp16 row-major, scale*log2e folded (8 elems/thread)
// blocks [512,1024): K fp16 frag-major [h][kt][t16][quad][n][j]
// blocks [1024,1536): V fp16 frag-major [h][kt][khalf][dhalf][quad][n][j],
//   rows permuted for in-register P: elem j holds row
//   kt*64 + khalf*32 + (j>>2)*16 + quad*4 + (j&3)
// blocks [1536,2560): mask -> per-lane u16 mlane[qt16][kt][lane];
//   bit (t16*4+r) = mask[qt16*16+(l&15)][kt*64 + t16*16 + (l>>4)*4 + r]
__global__ __launch_bounds__(256)
void prep_all(const float* __restrict__ Q, const float* __restrict__ K,
              const float* __restrict__ V, const int* __restrict__ mask,
              ushort_t* __restrict__ Qh, ushort_t* __restrict__ Kt,
              ushort_t* __restrict__ Vt, ushort_t* __restrict__ mlane)
{
    __shared__ u32 msh[16 * 257];   // 16.4 KB, 257-padded: conflict-free both phases
    const int bx = blockIdx.x;
    const int tid = threadIdx.x;
    union U8 { ushort_t u[8]; short8 v; };

    if (bx < 512) {
        const int e0 = (bx * 256 + tid) * 8;
        const float c = 0.17677669529663687f * 1.4426950408889634f;
        float4 a = *(const float4*)(Q + e0);
        float4 b = *(const float4*)(Q + e0 + 4);
        float f[8] = {a.x*c, a.y*c, a.z*c, a.w*c, b.x*c, b.y*c, b.z*c, b.w*c};
        U8 o;
#pragma unroll
        for (int i = 0; i < 8; ++i) o.u[i] = f2h(f[i]);
        *(short8*)(Qh + e0) = o.v;
    } else if (bx < 1024) {
        const int e0 = ((bx - 512) * 256 + tid) * 8;
        const int n = (e0 >> 3) & 15, quad = (e0 >> 7) & 3, t16 = (e0 >> 9) & 3;
        const int kt = (e0 >> 11) & 63, h = e0 >> 17;
        const int krow = kt * 64 + t16 * 16 + n;
        const float* src = K + ((size_t)h * S_ + krow) * D_ + quad * 8;
        float4 a = *(const float4*)src;
        float4 b = *(const float4*)(src + 4);
        float f[8] = {a.x, a.y, a.z, a.w, b.x, b.y, b.z, b.w};
        U8 o;
#pragma unroll
        for (int i = 0; i < 8; ++i) o.u[i] = f2h(f[i]);
        *(short8*)(Kt + e0) = o.v;
    } else if (bx < 1536) {
        const int e0 = ((bx - 1024) * 256 + tid) * 8;
        const int n = (e0 >> 3) & 15, quad = (e0 >> 7) & 3;
        const int dhalf = (e0 >> 9) & 1, khalf = (e0 >> 10) & 1;
        const int kt = (e0 >> 11) & 63, h = e0 >> 17;
        const int d = dhalf * 16 + n;
        U8 o;
#pragma unroll
        for (int j = 0; j < 8; ++j) {
            // nominal k' = quad*8 + j  ->  actual row (j>>2)*16 + quad*4 + (j&3)
            int krow = kt * 64 + khalf * 32 + (j >> 2) * 16 + quad * 4 + (j & 3);
            o.u[j] = f2h(V[((size_t)h * S_ + krow) * D_ + d]);
        }
        *(short8*)(Vt + e0) = o.v;
    } else {
        const int mb = bx - 1536;              // [0,1024)
        const int qt16 = mb >> 2, cc = mb & 3;
        // phase 1: coalesced int4 reads -> bool bytes in LDS (padded rows)
#pragma unroll
        for (int i = 0; i < 16; ++i) {
            int4 m4 = *(const int4*)(mask + (size_t)(qt16 * 16 + i) * S_ + cc * 1024 + tid * 4);
            u32 v = (m4.x != 0 ? 1u : 0u) | (m4.y != 0 ? 0x100u : 0u)
                  | (m4.z != 0 ? 0x10000u : 0u) | (m4.w != 0 ? 0x1000000u : 0u);
            msh[i * 257 + tid] = v;
        }
        __syncthreads();
        // phase 2: thread -> 4 u16 words = lanes g*4..g*4+3 of one kt.
        const int kt_local = tid >> 4, g = tid & 15;
        const int qd = g >> 2, n4 = g & 3;
        u32 o16[4] = {0, 0, 0, 0};
#pragma unroll
        for (int t16 = 0; t16 < 4; ++t16) {
            const int cbase = kt_local * 16 + t16 * 4 + qd;
#pragma unroll
            for (int b = 0; b < 4; ++b) {
                u32 v = msh[(n4 * 4 + b) * 257 + cbase];
                // bytes {0,1} -> nibble b0|b1<<1|b2<<2|b3<<3 (no carries)
                u32 nib = ((v * 0x01020408u) >> 24) & 0xFu;
                o16[b] |= nib << (t16 * 4);
            }
        }
        union { u32 w2[2]; short4v s; } pk;
        pk.w2[0] = o16[0] | (o16[1] << 16);
        pk.w2[1] = o16[2] | (o16[3] << 16);
        const int kt = cc * 16 + kt_local;
        *(short4v*)(mlane + ((size_t)(qt16 * 64 + kt) * 64 + g * 4)) = pk.s;
    }
}

// ---------- main MFMA flash kernel: reg-pipelined, scalar-addressed -----
// q-tile 32: 1024 blocks x 8 waves x 8-kt strips, 2 q-subtiles per wave.

__global__ __launch_bounds__(512, 4)
void attn_mfma(const ushort_t* __restrict__ Qh, const ushort_t* __restrict__ Kt,
               const ushort_t* __restrict__ Vt, const ushort_t* __restrict__ mlane,
               float* __restrict__ out)
{
    // LDS: epilogue tree-combine only. 4 slots x (32q x 33 + 32 lsum) f32.
    __shared__ __align__(16) float red[4 * (32 * 33 + 32)];   // 17.4 KB
    const int RQ = 32 * 33 + 32;

    // XCD-chunked swizzle: 1024 blocks = 8 XCDs x 128; each XCD = one head.
    const int bid = blockIdx.x;
    const int swz = (bid & 7) * 128 + (bid >> 3);
    const int h  = swz >> 7;
    const int qb = swz & 127;
    const int q0 = qb * 32;

    const int tid = threadIdx.x;
    const int w = tid >> 6, l = tid & 63;      // w = k-strip owner (8 waves)
    const int n16 = l & 15, quad = l >> 4;

    // SCALAR kt-strip origin: w is wave-uniform; force into SGPR so all
    // load addresses become {SGPR base + imm + fixed lane offset}.
    const int kt0 = __builtin_amdgcn_readfirstlane(w * 8);

    // scalar base pointers (h, qb, kt0 all SGPR)
    const ushort_t* Ktw  = Kt    + (size_t)h * 64 * 2048 + (size_t)kt0 * 2048;
    const ushort_t* Vtw  = Vt    + (size_t)h * 64 * 2048 + (size_t)kt0 * 2048;
    const ushort_t* mlw0 = mlane + ((size_t)(qb * 2) << 12) + kt0 * 64;        // qs=0
    const ushort_t* mlw1 = mlw0 + 4096;                                        // qs=1

    // Q fragments for 2 q-subtiles (lane l -> Q[qs*16+n16][quad*8+j])
    half8 qh[2];
#pragma unroll
    for (int qs = 0; qs < 2; ++qs)
        qh[qs] = *(const half8*)(Qh + ((size_t)h * S_ + q0 + qs * 16 + n16) * D_ + quad * 8);

    half8 ones;
#pragma unroll
    for (int i = 0; i < 8; ++i) ones[i] = (_Float16)1.0f;

    float4v o0[2], o1[2], lacc[2];
#pragma unroll
    for (int qs = 0; qs < 2; ++qs) {
        o0[qs] = (float4v){0.f, 0.f, 0.f, 0.f};
        o1[qs] = (float4v){0.f, 0.f, 0.f, 0.f};
        lacc[qs] = (float4v){0.f, 0.f, 0.f, 0.f};
    }

    const int fo = quad * 128 + n16 * 8;       // fixed per-lane offset (elems)

    // double-buffered tile registers: [parity][kh*2 + idx]
    half8 kb[2][4], vv[2][4];
    u32 mm[2][2];

    // LOADT: TI is a LITERAL tile index (0..7) -> scalar base + imm offsets,
    // zero per-load VALU. No waits here; compiler inserts s_waitcnt before use.
#define LOADT(p, TI) { \
    mm[p][0] = mlw0[(TI) * 64 + l]; \
    mm[p][1] = mlw1[(TI) * 64 + l]; \
    kb[p][0] = *(const half8*)(Ktw + (TI) * 2048 + fo); \
    kb[p][1] = *(const half8*)(Ktw + (TI) * 2048 + 512 + fo); \
    kb[p][2] = *(const half8*)(Ktw + (TI) * 2048 + 1024 + fo); \
    kb[p][3] = *(const half8*)(Ktw + (TI) * 2048 + 1536 + fo); \
    vv[p][0] = *(const half8*)(Vtw + (TI) * 2048 + fo); \
    vv[p][1] = *(const half8*)(Vtw + (TI) * 2048 + 512 + fo); \
    vv[p][2] = *(const half8*)(Vtw + (TI) * 2048 + 1024 + fo); \
    vv[p][3] = *(const half8*)(Vtw + (TI) * 2048 + 1536 + fo); \
}

#define COMPUTE(p) { \
    __builtin_amdgcn_s_setprio(1); \
    _Pragma("unroll") \
    for (int kh = 0; kh < 2; ++kh) { \
        _Pragma("unroll") \
        for (int qs = 0; qs < 2; ++qs) { \
            float4v c0 = {0.f, 0.f, 0.f, 0.f}; \
            float4v c1 = {0.f, 0.f, 0.f, 0.f}; \
            c0 = __builtin_amdgcn_mfma_f32_16x16x32_f16(kb[p][2*kh],   qh[qs], c0, 0, 0, 0); \
            c1 = __builtin_amdgcn_mfma_f32_16x16x32_f16(kb[p][2*kh+1], qh[qs], c1, 0, 0, 0); \
            float f0[4], f1[4]; \
            _Pragma("unroll") \
            for (int r = 0; r < 4; ++r) { \
                float e0 = EXP2(c0[r]); \
                float e1 = EXP2(c1[r]); \
                u32 k0 = SEXT_BIT(mm[p][qs], kh * 8 + r); \
                u32 k1 = SEXT_BIT(mm[p][qs], kh * 8 + 4 + r); \
                f0[r] = __uint_as_float(__float_as_uint(e0) & k0); \
                f1[r] = __uint_as_float(__float_as_uint(e1) & k1); \
            } \
            union { fp16x2 hh[4]; half8 h8; } pk; \
            pk.hh[0] = __builtin_amdgcn_cvt_pkrtz(f0[0], f0[1]); \
            pk.hh[1] = __builtin_amdgcn_cvt_pkrtz(f0[2], f0[3]); \
            pk.hh[2] = __builtin_amdgcn_cvt_pkrtz(f1[0], f1[1]); \
            pk.hh[3] = __builtin_amdgcn_cvt_pkrtz(f1[2], f1[3]); \
            const half8 pa = pk.h8; \
            o0[qs]   = __builtin_amdgcn_mfma_f32_16x16x32_f16(pa, vv[p][2*kh],   o0[qs],   0, 0, 0); \
            o1[qs]   = __builtin_amdgcn_mfma_f32_16x16x32_f16(pa, vv[p][2*kh+1], o1[qs],   0, 0, 0); \
            lacc[qs] = __builtin_amdgcn_mfma_f32_16x16x32_f16(pa, ones, lacc[qs], 0, 0, 0); \
        } \
    } \
    __builtin_amdgcn_s_setprio(0); \
}

    // software pipeline: prefetch tile i+1 while computing tile i.
    // sched_barrier(0) after each COMPUTE pins the next LOADT below it
    // (prevents hoisting -> register blowup/spill; R16 lesson).
    LOADT(0, 0);
    LOADT(1, 1);
    COMPUTE(0);
    __builtin_amdgcn_sched_barrier(0);
    LOADT(0, 2);
    COMPUTE(1);
    __builtin_amdgcn_sched_barrier(0);
    LOADT(1, 3);
    COMPUTE(0);
    __builtin_amdgcn_sched_barrier(0);
    LOADT(0, 4);
    COMPUTE(1);
    __builtin_amdgcn_sched_barrier(0);
    LOADT(1, 5);
    COMPUTE(0);
    __builtin_amdgcn_sched_barrier(0);
    LOADT(0, 6);
    COMPUTE(1);
    __builtin_amdgcn_sched_barrier(0);
    LOADT(1, 7);
    COMPUTE(0);
    __builtin_amdgcn_sched_barrier(0);
    COMPUTE(1);

#undef LOADT
#undef COMPUTE

    // ---- epilogue: 8-way tree combine in LDS (3 rounds, 4 slots) -------
    // accum layout: o0[qs][r] = O[q = qs*16 + quad*4 + r][d = n16], o1: d=16+n16
#define DUMP(slot) { \
    float* ro = red + (slot) * RQ; \
    _Pragma("unroll") for (int qs = 0; qs < 2; ++qs) \
    _Pragma("unroll") for (int r = 0; r < 4; ++r) { \
        const int q = qs * 16 + quad * 4 + r; \
        ro[q * 33 + n16]      = o0[qs][r]; \
        ro[q * 33 + 16 + n16] = o1[qs][r]; \
        if (n16 == 0) ro[32 * 33 + q] = lacc[qs][r]; \
    } }
#define ADDIN(slot) { \
    const float* ro = red + (slot) * RQ; \
    _Pragma("unroll") for (int qs = 0; qs < 2; ++qs) \
    _Pragma("unroll") for (int r = 0; r < 4; ++r) { \
        const int q = qs * 16 + quad * 4 + r; \
        o0[qs][r]   += ro[q * 33 + n16]; \
        o1[qs][r]   += ro[q * 33 + 16 + n16]; \
        lacc[qs][r] += ro[32 * 33 + q]; \
    } }

    if (w >= 4) DUMP(w - 4);
    __syncthreads();
    if (w < 4) ADDIN(w);
    __syncthreads();
    if (w == 2 || w == 3) DUMP(w - 2);
    __syncthreads();
    if (w < 2) ADDIN(w);
    __syncthreads();
    if (w == 1) DUMP(0);
    __syncthreads();
    if (w == 0) {
        const float* ro = red + 0 * RQ;
#pragma unroll
        for (int qs = 0; qs < 2; ++qs)
#pragma unroll
            for (int r = 0; r < 4; ++r) {
                const int q = qs * 16 + quad * 4 + r;
                const float s0 = o0[qs][r] + ro[q * 33 + n16];
                const float s1 = o1[qs][r] + ro[q * 33 + 16 + n16];
                const float sl = lacc[qs][r] + ro[32 * 33 + q];
                const float inv = 1.0f / sl;               // band => >0
                float* orow = out + ((size_t)h * S_ + q0 + q) * D_;
                orow[n16]      = s0 * inv;
                orow[16 + n16] = s1 * inv;
            }
    }
#undef DUMP
#undef ADDIN
}

// ---------------- fallback fp32 kernel (proven) ----------------

#define QT 64
#define KT 64
#define NSUB 4
#define KPT 16

__global__ __launch_bounds__(256, 2)
void sparse_attn_fp32(const float* __restrict__ Q, const float* __restrict__ K,
                      const float* __restrict__ V, const int* __restrict__ mask,
                      float* __restrict__ out)
{
    __shared__ float Ks[KT][D_];
    __shared__ float Vs[KT][D_];
    __shared__ float red_o[NSUB][QT][D_ + 1];
    __shared__ float red_l[NSUB][QT];

    const int h = blockIdx.y;
    const int q0 = blockIdx.x * QT;
    const int tid = threadIdx.x;
    const int ql = tid & 63;
    const int sub = tid >> 6;
    const int q = q0 + ql;
    const float scale = 0.17677669529663687f;

    float4 qreg[8];
    const float4* qrow = (const float4*)(Q + ((size_t)h * S_ + q) * D_);
#pragma unroll
    for (int i = 0; i < 8; ++i) qreg[i] = qrow[i];

    float o[D_];
#pragma unroll
    for (int d = 0; d < D_; ++d) o[d] = 0.f;
    float lsum0 = 0.f;

    const float* Kh = K + (size_t)h * S_ * D_;
    const float* Vh = V + (size_t)h * S_ * D_;

    for (int jt = 0; jt < S_; jt += KT) {
        __syncthreads();
        {
            const float4* gK = (const float4*)(Kh + (size_t)jt * D_);
            const float4* gV = (const float4*)(Vh + (size_t)jt * D_);
            float4* sK = (float4*)&Ks[0][0];
            float4* sV = (float4*)&Vs[0][0];
            sK[tid] = gK[tid]; sK[tid + 256] = gK[tid + 256];
            sV[tid] = gV[tid]; sV[tid + 256] = gV[tid + 256];
        }
        __syncthreads();

        int4 m4[4];
        {
            const int4* mr = (const int4*)(mask + (size_t)q * S_ + jt + sub * KPT);
#pragma unroll
            for (int i = 0; i < 4; ++i) m4[i] = mr[i];
        }
        const int* mb = (const int*)m4;

#pragma unroll
        for (int kk = 0; kk < KPT; ++kk) {
            const int jl = sub * KPT + kk;
            const float4* krow = (const float4*)&Ks[jl][0];
            float s = 0.f;
#pragma unroll
            for (int i = 0; i < 8; ++i) {
                float4 kv = krow[i];
                s += qreg[i].x * kv.x + qreg[i].y * kv.y + qreg[i].z * kv.z + qreg[i].w * kv.w;
            }
            const float p = mb[kk] ? __expf(s * scale) : 0.f;
            lsum0 += p;
            const float4* vrow = (const float4*)&Vs[jl][0];
#pragma unroll
            for (int i = 0; i < 8; ++i) {
                float4 vv = vrow[i];
                o[i * 4 + 0] += p * vv.x;
                o[i * 4 + 1] += p * vv.y;
                o[i * 4 + 2] += p * vv.z;
                o[i * 4 + 3] += p * vv.w;
            }
        }
    }

#pragma unroll
    for (int d = 0; d < D_; ++d) red_o[sub][ql][d] = o[d];
    red_l[sub][ql] = lsum0;
    __syncthreads();

    const int eq = tid & 63;
    const int dg = tid >> 6;
    float acc[8];
#pragma unroll
    for (int i = 0; i < 8; ++i) acc[i] = 0.f;
    float lsum = 0.f;
#pragma unroll
    for (int s2 = 0; s2 < NSUB; ++s2) {
        lsum += red_l[s2][eq];
#pragma unroll
        for (int i = 0; i < 8; ++i) acc[i] += red_o[s2][eq][dg * 8 + i];
    }
    const float inv = 1.0f / lsum;
    float* orow = out + ((size_t)h * S_ + q0 + eq) * D_ + dg * 8;
#pragma unroll
    for (int i = 0; i < 8; ++i) orow[i] = acc[i] * inv;
}

// ---------------- host ----------------

extern "C" void kernel_launch(void* const* d_in, const int* in_sizes, int n_in,
                              void* d_out, int out_size, void* d_ws, size_t ws_size,
                              hipStream_t stream) {
    const float* Q = (const float*)d_in[0];
    const float* K = (const float*)d_in[1];
    const float* V = (const float*)d_in[2];
    const int* mask = (const int*)d_in[3];
    float* out = (float*)d_out;

    const size_t MB = 1024 * 1024;
    if (ws_size < 8 * MB) {
        dim3 grid(S_ / QT, H_);
        sparse_attn_fp32<<<grid, 256, 0, stream>>>(Q, K, V, mask, out);
        return;
    }

    char* ws = (char*)d_ws;
    ushort_t* Qh = (ushort_t*)(ws + 0 * MB);
    ushort_t* Kt = (ushort_t*)(ws + 2 * MB);
    ushort_t* Vt = (ushort_t*)(ws + 4 * MB);
    ushort_t* mlane = (ushort_t*)(ws + 6 * MB);  // 2 MB

    prep_all<<<2560, 256, 0, stream>>>(Q, K, V, mask, Qh, Kt, Vt, mlane);
    attn_mfma<<<1024, 512, 0, stream>>>(Qh, Kt, Vt, mlane, out);
}

// Round 8
// 148.286 us; speedup vs baseline: 1.0254x; 1.0254x over previous
//
#include <hip/hip_runtime.h>
#include <hip/hip_bf16.h>

// SparseAttention B=1,H=8,S=4096,D=32 fp32; mask [S,S] as int32.
// R20: revert to R18 (proven best, 136.3us total; R19's scalar-addressing
// rewrite spilled: WRITE 4->34.7MB scratch, +14us). R18 loop pipeline and
// vector addressing kept VERBATIM. Two surgical deltas only:
//  (1) s_setprio(1)/(0) around COMPUTE (T5; attn-proven +4-7%, waves here
//      are independent & phase-diverse = the regime where it pays).
//  (2) parallel epilogue: 8 waves dump to 8 LDS slots -> 1 barrier ->
//      512 threads reduce in parallel (was 3-round tree, 6 barriers,
//      final rounds 1-wave serial). Saves ~1-2us.
// Spill tripwire: FETCH ~11MB / WRITE ~4MB expected; balloon = revert.
// Kept: 2-deep reg pipeline w/ parity-static indices + sched_barrier(0)
// fences, 1024 blocks x 512 thr, q-tile 32, 8 waves x 8-kt strips,
// barrier-free main loop, swapped-operand QK^T, V pre-permuted,
// per-lane u16 mask, ones-MFMA row-sum, head-per-XCD swizzle.

#define S_  4096
#define D_  32
#define H_  8

typedef _Float16 half8 __attribute__((ext_vector_type(8)));
typedef __fp16 fp16x2 __attribute__((ext_vector_type(2)));
typedef short short8 __attribute__((ext_vector_type(8)));
typedef short short4v __attribute__((ext_vector_type(4)));
typedef float float4v __attribute__((ext_vector_type(4)));
typedef unsigned short ushort_t;
typedef unsigned int u32;

#if __has_builtin(__builtin_amdgcn_exp2f)
#define EXP2(x) __builtin_amdgcn_exp2f(x)
#else
#define EXP2(x) exp2f(x)
#endif

#if __has_builtin(__builtin_amdgcn_sbfe)
#define SEXT_BIT(v, b) ((u32)__builtin_amdgcn_sbfe((int)(v), (b), 1))
#else
#define SEXT_BIT(v, b) ((u32)(((int)((v) << (31 - (b)))) >> 31))
#endif

__device__ inline ushort_t f2h(float x) {
    union { _Float16 h; ushort_t u; } c; c.h = (_Float16)x; return c.u;
}

// ---------------- fused pre-pass (unchanged from R13-R18, proven) --------
// blocks [0,512): Q fp16 row-major, scale*log2e folded (8 elems/thread)
// blocks [512,1024): K fp16 frag-major [h][kt][t16][quad][n][j]
// blocks [1024,1536): V fp16 frag-major [h][kt][khalf][dhalf][quad][n][j],
//   rows permuted for in-register P: elem j holds row
//   kt*64 + khalf*32 + (j>>2)*16 + quad*4 + (j&3)
// blocks [1536,2560): mask -> per-lane u16 mlane[qt16][kt][lane];
//   bit (t16*4+r) = mask[qt16*16+(l&15)][kt*64 + t16*16 + (l>>4)*4 + r]
__global__ __launch_bounds__(256)
void prep_all(const float* __restrict__ Q, const float* __restrict__ K,
              const float* __restrict__ V, const int* __restrict__ mask,
              ushort_t* __restrict__ Qh, ushort_t* __restrict__ Kt,
              ushort_t* __restrict__ Vt, ushort_t* __restrict__ mlane)
{
    __shared__ u32 msh[16 * 257];   // 16.4 KB, 257-padded: conflict-free both phases
    const int bx = blockIdx.x;
    const int tid = threadIdx.x;
    union U8 { ushort_t u[8]; short8 v; };

    if (bx < 512) {
        const int e0 = (bx * 256 + tid) * 8;
        const float c = 0.17677669529663687f * 1.4426950408889634f;
        float4 a = *(const float4*)(Q + e0);
        float4 b = *(const float4*)(Q + e0 + 4);
        float f[8] = {a.x*c, a.y*c, a.z*c, a.w*c, b.x*c, b.y*c, b.z*c, b.w*c};
        U8 o;
#pragma unroll
        for (int i = 0; i < 8; ++i) o.u[i] = f2h(f[i]);
        *(short8*)(Qh + e0) = o.v;
    } else if (bx < 1024) {
        const int e0 = ((bx - 512) * 256 + tid) * 8;
        const int n = (e0 >> 3) & 15, quad = (e0 >> 7) & 3, t16 = (e0 >> 9) & 3;
        const int kt = (e0 >> 11) & 63, h = e0 >> 17;
        const int krow = kt * 64 + t16 * 16 + n;
        const float* src = K + ((size_t)h * S_ + krow) * D_ + quad * 8;
        float4 a = *(const float4*)src;
        float4 b = *(const float4*)(src + 4);
        float f[8] = {a.x, a.y, a.z, a.w, b.x, b.y, b.z, b.w};
        U8 o;
#pragma unroll
        for (int i = 0; i < 8; ++i) o.u[i] = f2h(f[i]);
        *(short8*)(Kt + e0) = o.v;
    } else if (bx < 1536) {
        const int e0 = ((bx - 1024) * 256 + tid) * 8;
        const int n = (e0 >> 3) & 15, quad = (e0 >> 7) & 3;
        const int dhalf = (e0 >> 9) & 1, khalf = (e0 >> 10) & 1;
        const int kt = (e0 >> 11) & 63, h = e0 >> 17;
        const int d = dhalf * 16 + n;
        U8 o;
#pragma unroll
        for (int j = 0; j < 8; ++j) {
            // nominal k' = quad*8 + j  ->  actual row (j>>2)*16 + quad*4 + (j&3)
            int krow = kt * 64 + khalf * 32 + (j >> 2) * 16 + quad * 4 + (j & 3);
            o.u[j] = f2h(V[((size_t)h * S_ + krow) * D_ + d]);
        }
        *(short8*)(Vt + e0) = o.v;
    } else {
        const int mb = bx - 1536;              // [0,1024)
        const int qt16 = mb >> 2, cc = mb & 3;
        // phase 1: coalesced int4 reads -> bool bytes in LDS (padded rows)
#pragma unroll
        for (int i = 0; i < 16; ++i) {
            int4 m4 = *(const int4*)(mask + (size_t)(qt16 * 16 + i) * S_ + cc * 1024 + tid * 4);
            u32 v = (m4.x != 0 ? 1u : 0u) | (m4.y != 0 ? 0x100u : 0u)
                  | (m4.z != 0 ? 0x10000u : 0u) | (m4.w != 0 ? 0x1000000u : 0u);
            msh[i * 257 + tid] = v;
        }
        __syncthreads();
        // phase 2: thread -> 4 u16 words = lanes g*4..g*4+3 of one kt.
        const int kt_local = tid >> 4, g = tid & 15;
        const int qd = g >> 2, n4 = g & 3;
        u32 o16[4] = {0, 0, 0, 0};
#pragma unroll
        for (int t16 = 0; t16 < 4; ++t16) {
            const int cbase = kt_local * 16 + t16 * 4 + qd;
#pragma unroll
            for (int b = 0; b < 4; ++b) {
                u32 v = msh[(n4 * 4 + b) * 257 + cbase];
                // bytes {0,1} -> nibble b0|b1<<1|b2<<2|b3<<3 (no carries)
                u32 nib = ((v * 0x01020408u) >> 24) & 0xFu;
                o16[b] |= nib << (t16 * 4);
            }
        }
        union { u32 w2[2]; short4v s; } pk;
        pk.w2[0] = o16[0] | (o16[1] << 16);
        pk.w2[1] = o16[2] | (o16[3] << 16);
        const int kt = cc * 16 + kt_local;
        *(short4v*)(mlane + ((size_t)(qt16 * 64 + kt) * 64 + g * 4)) = pk.s;
    }
}

// ---------- main MFMA flash kernel: reg-pipelined, direct-from-L2 -------
// q-tile 32: 1024 blocks x 512 thr, 8 waves x 8-kt strips (R18 structure).

__global__ __launch_bounds__(512, 4)
void attn_mfma(const ushort_t* __restrict__ Qh, const ushort_t* __restrict__ Kt,
               const ushort_t* __restrict__ Vt, const ushort_t* __restrict__ mlane,
               float* __restrict__ out)
{
    // LDS: epilogue only. 8 slots x (32q x 33 + 32 lsum) f32 = 34.8 KB.
    __shared__ __align__(16) float red[8 * (32 * 33 + 32)];
    const int RQ = 32 * 33 + 32;

    // XCD-chunked swizzle: 1024 blocks = 8 XCDs x 128; each XCD = one head.
    const int bid = blockIdx.x;
    const int swz = (bid & 7) * 128 + (bid >> 3);
    const int h  = swz >> 7;
    const int qb = swz & 127;
    const int q0 = qb * 32;

    const int tid = threadIdx.x;
    const int w = tid >> 6, l = tid & 63;      // w = k-strip owner (8 waves)
    const int n16 = l & 15, quad = l >> 4;

    const ushort_t* mlw = mlane + ((size_t)(qb * 2) << 12);  // +qs<<12 per subtile

    // Q fragments for 2 q-subtiles (lane l -> Q[qs*16+n16][quad*8+j])
    half8 qh[2];
#pragma unroll
    for (int qs = 0; qs < 2; ++qs)
        qh[qs] = *(const half8*)(Qh + ((size_t)h * S_ + q0 + qs * 16 + n16) * D_ + quad * 8);

    half8 ones;
#pragma unroll
    for (int i = 0; i < 8; ++i) ones[i] = (_Float16)1.0f;

    float4v o0[2], o1[2], lacc[2];
#pragma unroll
    for (int qs = 0; qs < 2; ++qs) {
        o0[qs] = (float4v){0.f, 0.f, 0.f, 0.f};
        o1[qs] = (float4v){0.f, 0.f, 0.f, 0.f};
        lacc[qs] = (float4v){0.f, 0.f, 0.f, 0.f};
    }

    const int fo = quad * 128 + n16 * 8;       // per-lane offset inside a 512-elem frag group
    const ushort_t* Ktp = Kt + (size_t)h * 64 * 2048;
    const ushort_t* Vtp = Vt + (size_t)h * 64 * 2048;

    const int kt0 = w * 8;                     // 8 kt per wave

    // double-buffered tile registers: [parity][kh*2 + idx]
    half8 kb[2][4], vv[2][4];
    u32 mm[2][2];

    // LOADT: issue all loads for tile kt into parity p (no waits here; the
    // compiler places s_waitcnt before first USE in COMPUTE of parity p).
#define LOADT(p, kt) { \
    const ushort_t* tb = Ktp + (kt) * 2048; \
    const ushort_t* vb = Vtp + (kt) * 2048; \
    mm[p][0] = mlw[(kt) * 64 + l]; \
    mm[p][1] = mlw[4096 + (kt) * 64 + l]; \
    kb[p][0] = *(const half8*)(tb + fo); \
    kb[p][1] = *(const half8*)(tb + 512 + fo); \
    kb[p][2] = *(const half8*)(tb + 1024 + fo); \
    kb[p][3] = *(const half8*)(tb + 1536 + fo); \
    vv[p][0] = *(const half8*)(vb + fo); \
    vv[p][1] = *(const half8*)(vb + 512 + fo); \
    vv[p][2] = *(const half8*)(vb + 1024 + fo); \
    vv[p][3] = *(const half8*)(vb + 1536 + fo); \
}

#define COMPUTE(p) { \
    __builtin_amdgcn_s_setprio(1); \
    _Pragma("unroll") \
    for (int kh = 0; kh < 2; ++kh) { \
        _Pragma("unroll") \
        for (int qs = 0; qs < 2; ++qs) { \
            float4v c0 = {0.f, 0.f, 0.f, 0.f}; \
            float4v c1 = {0.f, 0.f, 0.f, 0.f}; \
            c0 = __builtin_amdgcn_mfma_f32_16x16x32_f16(kb[p][2*kh],   qh[qs], c0, 0, 0, 0); \
            c1 = __builtin_amdgcn_mfma_f32_16x16x32_f16(kb[p][2*kh+1], qh[qs], c1, 0, 0, 0); \
            float f0[4], f1[4]; \
            _Pragma("unroll") \
            for (int r = 0; r < 4; ++r) { \
                float e0 = EXP2(c0[r]); \
                float e1 = EXP2(c1[r]); \
                u32 k0 = SEXT_BIT(mm[p][qs], kh * 8 + r); \
                u32 k1 = SEXT_BIT(mm[p][qs], kh * 8 + 4 + r); \
                f0[r] = __uint_as_float(__float_as_uint(e0) & k0); \
                f1[r] = __uint_as_float(__float_as_uint(e1) & k1); \
            } \
            union { fp16x2 hh[4]; half8 h8; } pk; \
            pk.hh[0] = __builtin_amdgcn_cvt_pkrtz(f0[0], f0[1]); \
            pk.hh[1] = __builtin_amdgcn_cvt_pkrtz(f0[2], f0[3]); \
            pk.hh[2] = __builtin_amdgcn_cvt_pkrtz(f1[0], f1[1]); \
            pk.hh[3] = __builtin_amdgcn_cvt_pkrtz(f1[2], f1[3]); \
            const half8 pa = pk.h8; \
            o0[qs]   = __builtin_amdgcn_mfma_f32_16x16x32_f16(pa, vv[p][2*kh],   o0[qs],   0, 0, 0); \
            o1[qs]   = __builtin_amdgcn_mfma_f32_16x16x32_f16(pa, vv[p][2*kh+1], o1[qs],   0, 0, 0); \
            lacc[qs] = __builtin_amdgcn_mfma_f32_16x16x32_f16(pa, ones, lacc[qs], 0, 0, 0); \
        } \
    } \
    __builtin_amdgcn_s_setprio(0); \
}

    // software pipeline: prefetch tile i+1 while computing tile i.
    // sched_barrier(0) after each COMPUTE pins the next LOADT below it
    // (prevents hoisting -> register blowup/spill; R16/R19 lesson).
    LOADT(0, kt0 + 0);
    for (int i = 0; i < 6; i += 2) {
        LOADT(1, kt0 + i + 1);
        COMPUTE(0);
        __builtin_amdgcn_sched_barrier(0);
        LOADT(0, kt0 + i + 2);
        COMPUTE(1);
        __builtin_amdgcn_sched_barrier(0);
    }
    LOADT(1, kt0 + 7);
    COMPUTE(0);
    __builtin_amdgcn_sched_barrier(0);
    COMPUTE(1);

#undef LOADT
#undef COMPUTE

    // ---- epilogue: all 8 waves dump -> 1 barrier -> parallel reduce ----
    // accum layout: o0[qs][r] = O[q = qs*16 + quad*4 + r][d = n16], o1: d=16+n16
    {
        float* ro = red + w * RQ;
#pragma unroll
        for (int qs = 0; qs < 2; ++qs)
#pragma unroll
            for (int r = 0; r < 4; ++r) {
                const int q = qs * 16 + quad * 4 + r;
                ro[q * 33 + n16]      = o0[qs][r];
                ro[q * 33 + 16 + n16] = o1[qs][r];
                if (n16 == 0) ro[32 * 33 + q] = lacc[qs][r];
            }
    }
    __syncthreads();
    {
        // thread t: (q = t>>4, d = t&15) and d+16. 2 outputs/thread.
        const int q = tid >> 4, d = tid & 15;
        float s0 = 0.f, s1 = 0.f, sl = 0.f;
#pragma unroll
        for (int s = 0; s < 8; ++s) {
            const float* ro = red + s * RQ;
            s0 += ro[q * 33 + d];
            s1 += ro[q * 33 + 16 + d];
            sl += ro[32 * 33 + q];
        }
        const float inv = 1.0f / sl;               // band => >0
        float* orow = out + ((size_t)h * S_ + q0 + q) * D_;
        orow[d]      = s0 * inv;
        orow[16 + d] = s1 * inv;
    }
}

// ---------------- fallback fp32 kernel (proven) ----------------

#define QT 64
#define KT 64
#define NSUB 4
#define KPT 16

__global__ __launch_bounds__(256, 2)
void sparse_attn_fp32(const float* __restrict__ Q, const float* __restrict__ K,
                      const float* __restrict__ V, const int* __restrict__ mask,
                      float* __restrict__ out)
{
    __shared__ float Ks[KT][D_];
    __shared__ float Vs[KT][D_];
    __shared__ float red_o[NSUB][QT][D_ + 1];
    __shared__ float red_l[NSUB][QT];

    const int h = blockIdx.y;
    const int q0 = blockIdx.x * QT;
    const int tid = threadIdx.x;
    const int ql = tid & 63;
    const int sub = tid >> 6;
    const int q = q0 + ql;
    const float scale = 0.17677669529663687f;

    float4 qreg[8];
    const float4* qrow = (const float4*)(Q + ((size_t)h * S_ + q) * D_);
#pragma unroll
    for (int i = 0; i < 8; ++i) qreg[i] = qrow[i];

    float o[D_];
#pragma unroll
    for (int d = 0; d < D_; ++d) o[d] = 0.f;
    float lsum0 = 0.f;

    const float* Kh = K + (size_t)h * S_ * D_;
    const float* Vh = V + (size_t)h * S_ * D_;

    for (int jt = 0; jt < S_; jt += KT) {
        __syncthreads();
        {
            const float4* gK = (const float4*)(Kh + (size_t)jt * D_);
            const float4* gV = (const float4*)(Vh + (size_t)jt * D_);
            float4* sK = (float4*)&Ks[0][0];
            float4* sV = (float4*)&Vs[0][0];
            sK[tid] = gK[tid]; sK[tid + 256] = gK[tid + 256];
            sV[tid] = gV[tid]; sV[tid + 256] = gV[tid + 256];
        }
        __syncthreads();

        int4 m4[4];
        {
            const int4* mr = (const int4*)(mask + (size_t)q * S_ + jt + sub * KPT);
#pragma unroll
            for (int i = 0; i < 4; ++i) m4[i] = mr[i];
        }
        const int* mb = (const int*)m4;

#pragma unroll
        for (int kk = 0; kk < KPT; ++kk) {
            const int jl = sub * KPT + kk;
            const float4* krow = (const float4*)&Ks[jl][0];
            float s = 0.f;
#pragma unroll
            for (int i = 0; i < 8; ++i) {
                float4 kv = krow[i];
                s += qreg[i].x * kv.x + qreg[i].y * kv.y + qreg[i].z * kv.z + qreg[i].w * kv.w;
            }
            const float p = mb[kk] ? __expf(s * scale) : 0.f;
            lsum0 += p;
            const float4* vrow = (const float4*)&Vs[jl][0];
#pragma unroll
            for (int i = 0; i < 8; ++i) {
                float4 vv = vrow[i];
                o[i * 4 + 0] += p * vv.x;
                o[i * 4 + 1] += p * vv.y;
                o[i * 4 + 2] += p * vv.z;
                o[i * 4 + 3] += p * vv.w;
            }
        }
    }

#pragma unroll
    for (int d = 0; d < D_; ++d) red_o[sub][ql][d] = o[d];
    red_l[sub][ql] = lsum0;
    __syncthreads();

    const int eq = tid & 63;
    const int dg = tid >> 6;
    float acc[8];
#pragma unroll
    for (int i = 0; i < 8; ++i) acc[i] = 0.f;
    float lsum = 0.f;
#pragma unroll
    for (int s2 = 0; s2 < NSUB; ++s2) {
        lsum += red_l[s2][eq];
#pragma unroll
        for (int i = 0; i < 8; ++i) acc[i] += red_o[s2][eq][dg * 8 + i];
    }
    const float inv = 1.0f / lsum;
    float* orow = out + ((size_t)h * S_ + q0 + eq) * D_ + dg * 8;
#pragma unroll
    for (int i = 0; i < 8; ++i) orow[i] = acc[i] * inv;
}

// ---------------- host ----------------

extern "C" void kernel_launch(void* const* d_in, const int* in_sizes, int n_in,
                              void* d_out, int out_size, void* d_ws, size_t ws_size,
                              hipStream_t stream) {
    const float* Q = (const float*)d_in[0];
    const float* K = (const float*)d_in[1];
    const float* V = (const float*)d_in[2];
    const int* mask = (const int*)d_in[3];
    float* out = (float*)d_out;

    const size_t MB = 1024 * 1024;
    if (ws_size < 8 * MB) {
        dim3 grid(S_ / QT, H_);
        sparse_attn_fp32<<<grid, 256, 0, stream>>>(Q, K, V, mask, out);
        return;
    }

    char* ws = (char*)d_ws;
    ushort_t* Qh = (ushort_t*)(ws + 0 * MB);
    ushort_t* Kt = (ushort_t*)(ws + 2 * MB);
    ushort_t* Vt = (ushort_t*)(ws + 4 * MB);
    ushort_t* mlane = (ushort_t*)(ws + 6 * MB);  // 2 MB

    prep_all<<<2560, 256, 0, stream>>>(Q, K, V, mask, Qh, Kt, Vt, mlane);
    attn_mfma<<<1024, 512, 0, stream>>>(Qh, Kt, Vt, mlane, out);
}

// Round 10
// 134.053 us; speedup vs baseline: 1.1343x; 1.1062x over previous
//
#include <hip/hip_runtime.h>
#include <hip/hip_bf16.h>

// SparseAttention B=1,H=8,S=4096,D=32 fp32; mask [S,S] as int32.
// R22 (= R21 resubmit; R21 run died to infra, not the kernel).
// Single-variable isolation: R19 {setprio+scalar+unroll} and R20
// {setprio+parallel-epilogue} BOTH spilled (WRITE 32-35MB, attn ~50us);
// intersection = setprio (prime suspect for flipping the allocator; the
// 2-deep pipeline's live state sits at the regalloc boundary, rule #19).
// This round: EXACT R18 main loop (no setprio, loop-form pipeline,
// vector addressing, launch_bounds(512,4)) + ONLY the parallel epilogue
// (8 LDS slots -> 1 barrier -> 512-thread reduce; replaces 6-barrier
// tree). If spill returns -> epilogue guilty, full R18 revert next;
// if clean -> setprio convicted, expect ~133-135us total (new best).
// Spill tripwires: WRITE ~4MB, FETCH ~11.3MB.
// Kept: 2-deep reg pipeline w/ parity-static indices + sched_barrier(0),
// 1024 blocks x 512 thr, q-tile 32, 8 waves x 8-kt strips, barrier-free
// main loop, swapped-operand QK^T, V pre-permuted, per-lane u16 mask,
// ones-MFMA row-sum, head-per-XCD swizzle. Prep unchanged (proven).

#define S_  4096
#define D_  32
#define H_  8

typedef _Float16 half8 __attribute__((ext_vector_type(8)));
typedef __fp16 fp16x2 __attribute__((ext_vector_type(2)));
typedef short short8 __attribute__((ext_vector_type(8)));
typedef short short4v __attribute__((ext_vector_type(4)));
typedef float float4v __attribute__((ext_vector_type(4)));
typedef unsigned short ushort_t;
typedef unsigned int u32;

#if __has_builtin(__builtin_amdgcn_exp2f)
#define EXP2(x) __builtin_amdgcn_exp2f(x)
#else
#define EXP2(x) exp2f(x)
#endif

#if __has_builtin(__builtin_amdgcn_sbfe)
#define SEXT_BIT(v, b) ((u32)__builtin_amdgcn_sbfe((int)(v), (b), 1))
#else
#define SEXT_BIT(v, b) ((u32)(((int)((v) << (31 - (b)))) >> 31))
#endif

__device__ inline ushort_t f2h(float x) {
    union { _Float16 h; ushort_t u; } c; c.h = (_Float16)x; return c.u;
}

// ---------------- fused pre-pass (unchanged from R13-R18, proven) --------
// blocks [0,512): Q fp16 row-major, scale*log2e folded (8 elems/thread)
// blocks [512,1024): K fp16 frag-major [h][kt][t16][quad][n][j]
// blocks [1024,1536): V fp16 frag-major [h][kt][khalf][dhalf][quad][n][j],
//   rows permuted for in-register P: elem j holds row
//   kt*64 + khalf*32 + (j>>2)*16 + quad*4 + (j&3)
// blocks [1536,2560): mask -> per-lane u16 mlane[qt16][kt][lane];
//   bit (t16*4+r) = mask[qt16*16+(l&15)][kt*64 + t16*16 + (l>>4)*4 + r]
__global__ __launch_bounds__(256)
void prep_all(const float* __restrict__ Q, const float* __restrict__ K,
              const float* __restrict__ V, const int* __restrict__ mask,
              ushort_t* __restrict__ Qh, ushort_t* __restrict__ Kt,
              ushort_t* __restrict__ Vt, ushort_t* __restrict__ mlane)
{
    __shared__ u32 msh[16 * 257];   // 16.4 KB, 257-padded: conflict-free both phases
    const int bx = blockIdx.x;
    const int tid = threadIdx.x;
    union U8 { ushort_t u[8]; short8 v; };

    if (bx < 512) {
        const int e0 = (bx * 256 + tid) * 8;
        const float c = 0.17677669529663687f * 1.4426950408889634f;
        float4 a = *(const float4*)(Q + e0);
        float4 b = *(const float4*)(Q + e0 + 4);
        float f[8] = {a.x*c, a.y*c, a.z*c, a.w*c, b.x*c, b.y*c, b.z*c, b.w*c};
        U8 o;
#pragma unroll
        for (int i = 0; i < 8; ++i) o.u[i] = f2h(f[i]);
        *(short8*)(Qh + e0) = o.v;
    } else if (bx < 1024) {
        const int e0 = ((bx - 512) * 256 + tid) * 8;
        const int n = (e0 >> 3) & 15, quad = (e0 >> 7) & 3, t16 = (e0 >> 9) & 3;
        const int kt = (e0 >> 11) & 63, h = e0 >> 17;
        const int krow = kt * 64 + t16 * 16 + n;
        const float* src = K + ((size_t)h * S_ + krow) * D_ + quad * 8;
        float4 a = *(const float4*)src;
        float4 b = *(const float4*)(src + 4);
        float f[8] = {a.x, a.y, a.z, a.w, b.x, b.y, b.z, b.w};
        U8 o;
#pragma unroll
        for (int i = 0; i < 8; ++i) o.u[i] = f2h(f[i]);
        *(short8*)(Kt + e0) = o.v;
    } else if (bx < 1536) {
        const int e0 = ((bx - 1024) * 256 + tid) * 8;
        const int n = (e0 >> 3) & 15, quad = (e0 >> 7) & 3;
        const int dhalf = (e0 >> 9) & 1, khalf = (e0 >> 10) & 1;
        const int kt = (e0 >> 11) & 63, h = e0 >> 17;
        const int d = dhalf * 16 + n;
        U8 o;
#pragma unroll
        for (int j = 0; j < 8; ++j) {
            // nominal k' = quad*8 + j  ->  actual row (j>>2)*16 + quad*4 + (j&3)
            int krow = kt * 64 + khalf * 32 + (j >> 2) * 16 + quad * 4 + (j & 3);
            o.u[j] = f2h(V[((size_t)h * S_ + krow) * D_ + d]);
        }
        *(short8*)(Vt + e0) = o.v;
    } else {
        const int mb = bx - 1536;              // [0,1024)
        const int qt16 = mb >> 2, cc = mb & 3;
        // phase 1: coalesced int4 reads -> bool bytes in LDS (padded rows)
#pragma unroll
        for (int i = 0; i < 16; ++i) {
            int4 m4 = *(const int4*)(mask + (size_t)(qt16 * 16 + i) * S_ + cc * 1024 + tid * 4);
            u32 v = (m4.x != 0 ? 1u : 0u) | (m4.y != 0 ? 0x100u : 0u)
                  | (m4.z != 0 ? 0x10000u : 0u) | (m4.w != 0 ? 0x1000000u : 0u);
            msh[i * 257 + tid] = v;
        }
        __syncthreads();
        // phase 2: thread -> 4 u16 words = lanes g*4..g*4+3 of one kt.
        const int kt_local = tid >> 4, g = tid & 15;
        const int qd = g >> 2, n4 = g & 3;
        u32 o16[4] = {0, 0, 0, 0};
#pragma unroll
        for (int t16 = 0; t16 < 4; ++t16) {
            const int cbase = kt_local * 16 + t16 * 4 + qd;
#pragma unroll
            for (int b = 0; b < 4; ++b) {
                u32 v = msh[(n4 * 4 + b) * 257 + cbase];
                // bytes {0,1} -> nibble b0|b1<<1|b2<<2|b3<<3 (no carries)
                u32 nib = ((v * 0x01020408u) >> 24) & 0xFu;
                o16[b] |= nib << (t16 * 4);
            }
        }
        union { u32 w2[2]; short4v s; } pk;
        pk.w2[0] = o16[0] | (o16[1] << 16);
        pk.w2[1] = o16[2] | (o16[3] << 16);
        const int kt = cc * 16 + kt_local;
        *(short4v*)(mlane + ((size_t)(qt16 * 64 + kt) * 64 + g * 4)) = pk.s;
    }
}

// ---------- main MFMA flash kernel: reg-pipelined, direct-from-L2 -------
// q-tile 32: 1024 blocks x 512 thr, 8 waves x 8-kt strips (R18 structure,
// byte-identical main loop; NO setprio).

__global__ __launch_bounds__(512, 4)
void attn_mfma(const ushort_t* __restrict__ Qh, const ushort_t* __restrict__ Kt,
               const ushort_t* __restrict__ Vt, const ushort_t* __restrict__ mlane,
               float* __restrict__ out)
{
    // LDS: epilogue only. 8 slots x (32q x 33 + 32 lsum) f32 = 34.8 KB.
    __shared__ __align__(16) float red[8 * (32 * 33 + 32)];
    const int RQ = 32 * 33 + 32;

    // XCD-chunked swizzle: 1024 blocks = 8 XCDs x 128; each XCD = one head.
    const int bid = blockIdx.x;
    const int swz = (bid & 7) * 128 + (bid >> 3);
    const int h  = swz >> 7;
    const int qb = swz & 127;
    const int q0 = qb * 32;

    const int tid = threadIdx.x;
    const int w = tid >> 6, l = tid & 63;      // w = k-strip owner (8 waves)
    const int n16 = l & 15, quad = l >> 4;

    const ushort_t* mlw = mlane + ((size_t)(qb * 2) << 12);  // +qs<<12 per subtile

    // Q fragments for 2 q-subtiles (lane l -> Q[qs*16+n16][quad*8+j])
    half8 qh[2];
#pragma unroll
    for (int qs = 0; qs < 2; ++qs)
        qh[qs] = *(const half8*)(Qh + ((size_t)h * S_ + q0 + qs * 16 + n16) * D_ + quad * 8);

    half8 ones;
#pragma unroll
    for (int i = 0; i < 8; ++i) ones[i] = (_Float16)1.0f;

    float4v o0[2], o1[2], lacc[2];
#pragma unroll
    for (int qs = 0; qs < 2; ++qs) {
        o0[qs] = (float4v){0.f, 0.f, 0.f, 0.f};
        o1[qs] = (float4v){0.f, 0.f, 0.f, 0.f};
        lacc[qs] = (float4v){0.f, 0.f, 0.f, 0.f};
    }

    const int fo = quad * 128 + n16 * 8;       // per-lane offset inside a 512-elem frag group
    const ushort_t* Ktp = Kt + (size_t)h * 64 * 2048;
    const ushort_t* Vtp = Vt + (size_t)h * 64 * 2048;

    const int kt0 = w * 8;                     // 8 kt per wave

    // double-buffered tile registers: [parity][kh*2 + idx]
    half8 kb[2][4], vv[2][4];
    u32 mm[2][2];

    // LOADT: issue all loads for tile kt into parity p (no waits here; the
    // compiler places s_waitcnt before first USE in COMPUTE of parity p).
#define LOADT(p, kt) { \
    const ushort_t* tb = Ktp + (kt) * 2048; \
    const ushort_t* vb = Vtp + (kt) * 2048; \
    mm[p][0] = mlw[(kt) * 64 + l]; \
    mm[p][1] = mlw[4096 + (kt) * 64 + l]; \
    kb[p][0] = *(const half8*)(tb + fo); \
    kb[p][1] = *(const half8*)(tb + 512 + fo); \
    kb[p][2] = *(const half8*)(tb + 1024 + fo); \
    kb[p][3] = *(const half8*)(tb + 1536 + fo); \
    vv[p][0] = *(const half8*)(vb + fo); \
    vv[p][1] = *(const half8*)(vb + 512 + fo); \
    vv[p][2] = *(const half8*)(vb + 1024 + fo); \
    vv[p][3] = *(const half8*)(vb + 1536 + fo); \
}

#define COMPUTE(p) { \
    _Pragma("unroll") \
    for (int kh = 0; kh < 2; ++kh) { \
        _Pragma("unroll") \
        for (int qs = 0; qs < 2; ++qs) { \
            float4v c0 = {0.f, 0.f, 0.f, 0.f}; \
            float4v c1 = {0.f, 0.f, 0.f, 0.f}; \
            c0 = __builtin_amdgcn_mfma_f32_16x16x32_f16(kb[p][2*kh],   qh[qs], c0, 0, 0, 0); \
            c1 = __builtin_amdgcn_mfma_f32_16x16x32_f16(kb[p][2*kh+1], qh[qs], c1, 0, 0, 0); \
            float f0[4], f1[4]; \
            _Pragma("unroll") \
            for (int r = 0; r < 4; ++r) { \
                float e0 = EXP2(c0[r]); \
                float e1 = EXP2(c1[r]); \
                u32 k0 = SEXT_BIT(mm[p][qs], kh * 8 + r); \
                u32 k1 = SEXT_BIT(mm[p][qs], kh * 8 + 4 + r); \
                f0[r] = __uint_as_float(__float_as_uint(e0) & k0); \
                f1[r] = __uint_as_float(__float_as_uint(e1) & k1); \
            } \
            union { fp16x2 hh[4]; half8 h8; } pk; \
            pk.hh[0] = __builtin_amdgcn_cvt_pkrtz(f0[0], f0[1]); \
            pk.hh[1] = __builtin_amdgcn_cvt_pkrtz(f0[2], f0[3]); \
            pk.hh[2] = __builtin_amdgcn_cvt_pkrtz(f1[0], f1[1]); \
            pk.hh[3] = __builtin_amdgcn_cvt_pkrtz(f1[2], f1[3]); \
            const half8 pa = pk.h8; \
            o0[qs]   = __builtin_amdgcn_mfma_f32_16x16x32_f16(pa, vv[p][2*kh],   o0[qs],   0, 0, 0); \
            o1[qs]   = __builtin_amdgcn_mfma_f32_16x16x32_f16(pa, vv[p][2*kh+1], o1[qs],   0, 0, 0); \
            lacc[qs] = __builtin_amdgcn_mfma_f32_16x16x32_f16(pa, ones, lacc[qs], 0, 0, 0); \
        } \
    } \
}

    // software pipeline: prefetch tile i+1 while computing tile i.
    // sched_barrier(0) after each COMPUTE pins the next LOADT below it
    // (prevents hoisting -> register blowup/spill; R16/R19 lesson).
    LOADT(0, kt0 + 0);
    for (int i = 0; i < 6; i += 2) {
        LOADT(1, kt0 + i + 1);
        COMPUTE(0);
        __builtin_amdgcn_sched_barrier(0);
        LOADT(0, kt0 + i + 2);
        COMPUTE(1);
        __builtin_amdgcn_sched_barrier(0);
    }
    LOADT(1, kt0 + 7);
    COMPUTE(0);
    __builtin_amdgcn_sched_barrier(0);
    COMPUTE(1);

#undef LOADT
#undef COMPUTE

    // ---- epilogue: all 8 waves dump -> 1 barrier -> parallel reduce ----
    // accum layout: o0[qs][r] = O[q = qs*16 + quad*4 + r][d = n16], o1: d=16+n16
    {
        float* ro = red + w * RQ;
#pragma unroll
        for (int qs = 0; qs < 2; ++qs)
#pragma unroll
            for (int r = 0; r < 4; ++r) {
                const int q = qs * 16 + quad * 4 + r;
                ro[q * 33 + n16]      = o0[qs][r];
                ro[q * 33 + 16 + n16] = o1[qs][r];
                if (n16 == 0) ro[32 * 33 + q] = lacc[qs][r];
            }
    }
    __syncthreads();
    {
        // thread t: (q = t>>4, d = t&15) and d+16. 2 outputs/thread.
        const int q = tid >> 4, d = tid & 15;
        float s0 = 0.f, s1 = 0.f, sl = 0.f;
#pragma unroll
        for (int s = 0; s < 8; ++s) {
            const float* ro = red + s * RQ;
            s0 += ro[q * 33 + d];
            s1 += ro[q * 33 + 16 + d];
            sl += ro[32 * 33 + q];
        }
        const float inv = 1.0f / sl;               // band => >0
        float* orow = out + ((size_t)h * S_ + q0 + q) * D_;
        orow[d]      = s0 * inv;
        orow[16 + d] = s1 * inv;
    }
}

// ---------------- fallback fp32 kernel (proven) ----------------

#define QT 64
#define KT 64
#define NSUB 4
#define KPT 16

__global__ __launch_bounds__(256, 2)
void sparse_attn_fp32(const float* __restrict__ Q, const float* __restrict__ K,
                      const float* __restrict__ V, const int* __restrict__ mask,
                      float* __restrict__ out)
{
    __shared__ float Ks[KT][D_];
    __shared__ float Vs[KT][D_];
    __shared__ float red_o[NSUB][QT][D_ + 1];
    __shared__ float red_l[NSUB][QT];

    const int h = blockIdx.y;
    const int q0 = blockIdx.x * QT;
    const int tid = threadIdx.x;
    const int ql = tid & 63;
    const int sub = tid >> 6;
    const int q = q0 + ql;
    const float scale = 0.17677669529663687f;

    float4 qreg[8];
    const float4* qrow = (const float4*)(Q + ((size_t)h * S_ + q) * D_);
#pragma unroll
    for (int i = 0; i < 8; ++i) qreg[i] = qrow[i];

    float o[D_];
#pragma unroll
    for (int d = 0; d < D_; ++d) o[d] = 0.f;
    float lsum0 = 0.f;

    const float* Kh = K + (size_t)h * S_ * D_;
    const float* Vh = V + (size_t)h * S_ * D_;

    for (int jt = 0; jt < S_; jt += KT) {
        __syncthreads();
        {
            const float4* gK = (const float4*)(Kh + (size_t)jt * D_);
            const float4* gV = (const float4*)(Vh + (size_t)jt * D_);
            float4* sK = (float4*)&Ks[0][0];
            float4* sV = (float4*)&Vs[0][0];
            sK[tid] = gK[tid]; sK[tid + 256] = gK[tid + 256];
            sV[tid] = gV[tid]; sV[tid + 256] = gV[tid + 256];
        }
        __syncthreads();

        int4 m4[4];
        {
            const int4* mr = (const int4*)(mask + (size_t)q * S_ + jt + sub * KPT);
#pragma unroll
            for (int i = 0; i < 4; ++i) m4[i] = mr[i];
        }
        const int* mb = (const int*)m4;

#pragma unroll
        for (int kk = 0; kk < KPT; ++kk) {
            const int jl = sub * KPT + kk;
            const float4* krow = (const float4*)&Ks[jl][0];
            float s = 0.f;
#pragma unroll
            for (int i = 0; i < 8; ++i) {
                float4 kv = krow[i];
                s += qreg[i].x * kv.x + qreg[i].y * kv.y + qreg[i].z * kv.z + qreg[i].w * kv.w;
            }
            const float p = mb[kk] ? __expf(s * scale) : 0.f;
            lsum0 += p;
            const float4* vrow = (const float4*)&Vs[jl][0];
#pragma unroll
            for (int i = 0; i < 8; ++i) {
                float4 vv = vrow[i];
                o[i * 4 + 0] += p * vv.x;
                o[i * 4 + 1] += p * vv.y;
                o[i * 4 + 2] += p * vv.z;
                o[i * 4 + 3] += p * vv.w;
            }
        }
    }

#pragma unroll
    for (int d = 0; d < D_; ++d) red_o[sub][ql][d] = o[d];
    red_l[sub][ql] = lsum0;
    __syncthreads();

    const int eq = tid & 63;
    const int dg = tid >> 6;
    float acc[8];
#pragma unroll
    for (int i = 0; i < 8; ++i) acc[i] = 0.f;
    float lsum = 0.f;
#pragma unroll
    for (int s2 = 0; s2 < NSUB; ++s2) {
        lsum += red_l[s2][eq];
#pragma unroll
        for (int i = 0; i < 8; ++i) acc[i] += red_o[s2][eq][dg * 8 + i];
    }
    const float inv = 1.0f / lsum;
    float* orow = out + ((size_t)h * S_ + q0 + eq) * D_ + dg * 8;
#pragma unroll
    for (int i = 0; i < 8; ++i) orow[i] = acc[i] * inv;
}

// ---------------- host ----------------

extern "C" void kernel_launch(void* const* d_in, const int* in_sizes, int n_in,
                              void* d_out, int out_size, void* d_ws, size_t ws_size,
                              hipStream_t stream) {
    const float* Q = (const float*)d_in[0];
    const float* K = (const float*)d_in[1];
    const float* V = (const float*)d_in[2];
    const int* mask = (const int*)d_in[3];
    float* out = (float*)d_out;

    const size_t MB = 1024 * 1024;
    if (ws_size < 8 * MB) {
        dim3 grid(S_ / QT, H_);
        sparse_attn_fp32<<<grid, 256, 0, stream>>>(Q, K, V, mask, out);
        return;
    }

    char* ws = (char*)d_ws;
    ushort_t* Qh = (ushort_t*)(ws + 0 * MB);
    ushort_t* Kt = (ushort_t*)(ws + 2 * MB);
    ushort_t* Vt = (ushort_t*)(ws + 4 * MB);
    ushort_t* mlane = (ushort_t*)(ws + 6 * MB);  // 2 MB

    prep_all<<<2560, 256, 0, stream>>>(Q, K, V, mask, Qh, Kt, Vt, mlane);
    attn_mfma<<<1024, 512, 0, stream>>>(Qh, Kt, Vt, mlane, out);
}